// Round 8
// baseline (462.821 us; speedup 1.0000x reference)
//
#include <hip/hip_runtime.h>
#include <hip/hip_bf16.h>

// ---------------------------------------------------------------------------
// QuantizedLinear: out[M,N] = (x[M,K] @ (Wq[N,K]*s[N,1]).T) + b[N]
// INT8 path (R6-validated, absmax 7.0): w -> i8 exact, x -> i8 per-row quant,
// mfma_i32_16x16x64_i8, epilogue acc*sx[m]*s[n]+b.
// Round 8: B-direct-to-registers. R6/R7 showed LDS-read + MFMA fully serial
// (within-wave rdAB->mfma chain; LDS cyc ~ MFMA cyc). Now only A goes through
// LDS (16 reads/block-tile = 192 cyc vs MFMA 326 cyc); B frags are loaded
// per-wave from global (16B/lane dwordx4, exact MFMA layout), double-buffered
// one tile ahead in named register sets; compiler's reg-dependency vmcnt
// hides them under MFMA. One {vmcnt; s_barrier} per tile. Ring-3 A = 24 KiB.
// ---------------------------------------------------------------------------

typedef __attribute__((ext_vector_type(4))) int   i32x4;
typedef __attribute__((ext_vector_type(4))) float f32x4;
typedef __attribute__((ext_vector_type(4))) unsigned int u32x4;

// ---- w: fp32 (integer-valued) -> i8, exact ---------------------------------
__device__ static inline unsigned int pack4(int q0, int q1, int q2, int q3) {
    return (unsigned)(q0 & 255) | ((unsigned)(q1 & 255) << 8) |
           ((unsigned)(q2 & 255) << 16) | ((unsigned)(q3 & 255) << 24);
}

__global__ void w_to_i8(const float* __restrict__ in,
                        u32x4* __restrict__ out, long n16) {
    const long stride = (long)gridDim.x * blockDim.x;
    for (long i = (long)blockIdx.x * blockDim.x + threadIdx.x; i < n16; i += stride) {
        const f32x4* p = reinterpret_cast<const f32x4*>(in) + i * 4;
        u32x4 o;
#pragma unroll
        for (int v = 0; v < 4; ++v) {
            f32x4 f = p[v];
            o[v] = pack4(__float2int_rn(f[0]), __float2int_rn(f[1]),
                         __float2int_rn(f[2]), __float2int_rn(f[3]));
        }
        out[i] = o;
    }
}

// ---- x: per-row absmax quant to i8; sx[row] = rowmax/127 -------------------
__global__ void x_quant_i8(const float* __restrict__ x,
                           unsigned int* __restrict__ xq,
                           float* __restrict__ sx, int K) {
    const int row = blockIdx.x;
    const int tid = threadIdx.x;
    const float* xr = x + (size_t)row * K;
    float m = 0.f;
    for (int b = tid * 16; b < K; b += blockDim.x * 16) {
        const f32x4* p = (const f32x4*)(xr + b);
#pragma unroll
        for (int v = 0; v < 4; ++v) {
            f32x4 f = p[v];
            m = fmaxf(m, fmaxf(fmaxf(fabsf(f[0]), fabsf(f[1])),
                               fmaxf(fabsf(f[2]), fabsf(f[3]))));
        }
    }
#pragma unroll
    for (int off = 32; off; off >>= 1) m = fmaxf(m, __shfl_xor(m, off));
    __shared__ float red[8];
    if ((tid & 63) == 0) red[tid >> 6] = m;
    __syncthreads();
    const int nw = blockDim.x >> 6;
    m = red[0];
    for (int i = 1; i < nw; ++i) m = fmaxf(m, red[i]);
    const float inv = (m > 0.f) ? 127.0f / m : 0.f;
    if (tid == 0) sx[row] = m * (1.0f / 127.0f);
    for (int b = tid * 16; b < K; b += blockDim.x * 16) {
        const f32x4* p = (const f32x4*)(xr + b);
        u32x4 o;
#pragma unroll
        for (int v = 0; v < 4; ++v) {
            f32x4 f = p[v];
            int q0 = min(127, max(-127, __float2int_rn(f[0] * inv)));
            int q1 = min(127, max(-127, __float2int_rn(f[1] * inv)));
            int q2 = min(127, max(-127, __float2int_rn(f[2] * inv)));
            int q3 = min(127, max(-127, __float2int_rn(f[3] * inv)));
            o[v] = pack4(q0, q1, q2, q3);
        }
        *reinterpret_cast<u32x4*>((char*)xq + (size_t)row * K + b) = o;
    }
}

// ---------------------------------------------------------------------------
// i8 GEMM. Tile 128x128, BK=64. 256 thr = 4 waves (2M x 2N), per-wave 64x64.
// LDS 24 KiB: A-only ring-3 (slot 8 KiB = 128 rows x 64 i8). B: direct
// global->reg, 4 dwordx4/wave/tile, dbuf (sets b0/b1, pair-unrolled loop).
// vmcnt ledger (per tile: B 4 loads + A-stage 2 gloads):
//   steady WAIT_VM(6) = younger[B(t+1):4, sA(t+2):2] -> retires sA(t+1);
//   tail NT-2: WAIT_VM(4); compiler's reg-dep vmcnt covers B sets.
// Swizzle (R6/R7-verified, 0 conflicts): phys 16B chunk ^= (row>>1)&3,
// pre-swizzled global source, linear LDS dest (rule #21).
// ---------------------------------------------------------------------------

#define GLOAD16(src, dst) __builtin_amdgcn_global_load_lds( \
    (const __attribute__((address_space(1))) void*)(src),   \
    (__attribute__((address_space(3))) void*)(dst), 16, 0, 0)

#define FENCE() asm volatile("" ::: "memory")
#define BAR()  do { FENCE(); __builtin_amdgcn_s_barrier(); FENCE(); } while (0)
#define WAIT_VM(n) asm volatile("s_waitcnt vmcnt(" #n ")" ::: "memory")

__global__ __launch_bounds__(256, 3)
void qlinear_gemm_i8bd(const char* __restrict__ A,   // [M,K] i8
                       const char* __restrict__ B,   // [N,K] i8
                       const float* __restrict__ sx, // [M] row scales of x
                       const float* __restrict__ scales,  // [N]
                       const float* __restrict__ bias,    // [N]
                       float* __restrict__ C,             // [M,N] f32
                       int M, int N, int K, int nbx) {
    __shared__ __align__(128) char smem[24576];

    const int tid  = threadIdx.x;
    const int lane = tid & 63;
    const int wid  = tid >> 6;
    const int mslab = (wid >> 1) * 64;   // 2 M-slabs
    const int nslab = (wid & 1) * 64;    // 2 N-slabs

    // T1: bijective XCD swizzle (m204); bcol-fastest (A panel L2-resident)
    const int nwg = gridDim.x;
    const int q = nwg >> 3, r = nwg & 7;
    const int xcd = blockIdx.x & 7, boff_ = blockIdx.x >> 3;
    const int swz = (xcd < r ? xcd * (q + 1) : r * (q + 1) + (xcd - r) * q) + boff_;
    const int bcol = swz % nbx;
    const int brow = swz / nbx;

    const char* Ag = A + (size_t)brow * 128 * K;
    const char* Bg = B + (size_t)bcol * 128 * K;

    // ---- A staging: 512 chunks/slot; chunk c -> row c>>2, phys slot c&3.
    const int c0 = tid, c1 = tid + 256;
    const int r0 = c0 >> 2, p0 = c0 & 3;
    const int r1 = c1 >> 2, p1 = c1 & 3;
    const size_t g0 = (size_t)r0 * K + ((p0 ^ ((r0 >> 1) & 3)) << 4);
    const size_t g1 = (size_t)r1 * K + ((p1 ^ ((r1 >> 1) & 3)) << 4);

    auto stageA = [&](int sl, int t) {
        const size_t ko = (size_t)t * 64;
        char* base = smem + sl * 8192;
        GLOAD16(Ag + g0 + ko, base + c0 * 16);
        GLOAD16(Ag + g1 + ko, base + c1 * 16);
    };

    // ---- A LDS reads: row = mslab + mi*16 + (lane&15); phys chunk =
    // (lane>>4) ^ ((lane>>1)&3).
    const int cph  = ((lane >> 4) ^ ((lane >> 1) & 3)) << 4;
    const int aoff = (mslab + (lane & 15)) * 64 + cph;

    // ---- B direct: lane base; frag ni at +ni*16 rows, tile t at +t*64 ----
    const char* Bl = Bg + (size_t)(nslab + (lane & 15)) * K + ((lane >> 4) << 4);

    i32x4 acc[4][4] = {};
    i32x4 af[4], b0s[4], b1s[4];

    auto rdA = [&](int sl) {
        const char* pa = smem + sl * 8192 + aoff;
#pragma unroll
        for (int mi = 0; mi < 4; ++mi) af[mi] = *(const i32x4*)(pa + mi * 1024);
    };
    auto loadB = [&](int t, i32x4 (&b)[4]) {
        const char* p = Bl + (size_t)t * 64;
#pragma unroll
        for (int ni = 0; ni < 4; ++ni)
            b[ni] = *(const i32x4*)(p + (size_t)ni * 16 * K);
    };
    auto mfma16 = [&](const i32x4 (&b)[4]) {
        __builtin_amdgcn_s_setprio(1);
#pragma unroll
        for (int mi = 0; mi < 4; ++mi)
#pragma unroll
            for (int ni = 0; ni < 4; ++ni)
                acc[mi][ni] = __builtin_amdgcn_mfma_i32_16x16x64_i8(
                    af[mi], b[ni], acc[mi][ni], 0, 0, 0);
        __builtin_amdgcn_s_setprio(0);
    };

    const int NT = K / 64;   // even, >= 4 (dispatch guard)

    // ---- prologue: A slots 0,1 staged; B(0) -> b0s ----
    stageA(0, 0); stageA(1, 1);
    loadB(0, b0s);
    WAIT_VM(6); BAR();       // retire sA(0); keep [sA(1):2, B(0):4]

    // ---- main loop: NT-2 full iters, pair-unrolled (NT even) ----
    int sl = 0;
    for (int t = 0; t < NT - 2; t += 2) {
        // even body: consume b0s, prefetch b1s
        loadB(t + 1, b1s);
        { int s2 = sl + 2; if (s2 >= 3) s2 -= 3; stageA(s2, t + 2); }
        rdA(sl);
        mfma16(b0s);
        WAIT_VM(6); BAR();   // retire sA(t+1); keep [B(t+1):4, sA(t+2):2]
        sl = (sl == 2) ? 0 : sl + 1;
        // odd body: consume b1s, prefetch b0s
        loadB(t + 2, b0s);
        { int s2 = sl + 2; if (s2 >= 3) s2 -= 3; stageA(s2, t + 3); }
        rdA(sl);
        mfma16(b1s);
        WAIT_VM(6); BAR();   // retire sA(t+2); keep [B(t+2):4, sA(t+3):2]
        sl = (sl == 2) ? 0 : sl + 1;
    }
    // t = NT-2 (even; current set b0s)
    loadB(NT - 1, b1s);
    rdA(sl);
    mfma16(b0s);
    WAIT_VM(4); BAR();       // retire sA(NT-1); keep [B(NT-1):4]
    sl = (sl == 2) ? 0 : sl + 1;
    // t = NT-1
    rdA(sl);
    mfma16(b1s);             // compiler waits B(NT-1) reg-dep

    // ---- epilogue: C/D layout col=lane&15, row=(lane>>4)*4+j ----
    const int lc  = lane & 15;
    const int lr4 = (lane >> 4) * 4;
    float sarr[4], barr[4];
#pragma unroll
    for (int ni = 0; ni < 4; ++ni) {
        const int n = bcol * 128 + nslab + ni * 16 + lc;
        sarr[ni] = scales[n];
        barr[ni] = bias[n];
    }
#pragma unroll
    for (int mi = 0; mi < 4; ++mi) {
        const int mb = brow * 128 + mslab + mi * 16 + lr4;
        const f32x4 sxv = *(const f32x4*)&sx[mb];
#pragma unroll
        for (int j = 0; j < 4; ++j) {
            const size_t rowoff = (size_t)(mb + j) * N;
            const float sm = sxv[j];
#pragma unroll
            for (int ni = 0; ni < 4; ++ni) {
                const int n = bcol * 128 + nslab + ni * 16 + lc;
                C[rowoff + n] = fmaf((float)acc[mi][ni][j], sm * sarr[ni], barr[ni]);
            }
        }
    }
}

// ---- Fallback: plain fp32 tiled GEMM, correctness insurance ----------------
__global__ void qlinear_fallback(const float* __restrict__ A,
                                 const float* __restrict__ B,
                                 const float* __restrict__ scales,
                                 const float* __restrict__ bias,
                                 float* __restrict__ C, int M, int N, int K) {
    __shared__ float As[16][17], Bs[16][17];
    const int tx = threadIdx.x, ty = threadIdx.y;
    const int row = blockIdx.y * 16 + ty;
    const int col = blockIdx.x * 16 + tx;
    float acc = 0.f;
    for (int k0 = 0; k0 < K; k0 += 16) {
        As[ty][tx] = A[(long)row * K + k0 + tx];
        Bs[ty][tx] = B[(long)(blockIdx.x * 16 + ty) * K + k0 + tx];
        __syncthreads();
#pragma unroll
        for (int kk = 0; kk < 16; ++kk) acc += As[ty][kk] * Bs[tx][kk];
        __syncthreads();
    }
    C[(long)row * N + col] = fmaf(acc, scales[col], bias[col]);
}

extern "C" void kernel_launch(void* const* d_in, const int* in_sizes, int n_in,
                              void* d_out, int out_size, void* d_ws, size_t ws_size,
                              hipStream_t stream) {
    const float* x      = (const float*)d_in[0];
    const float* w      = (const float*)d_in[1];
    const float* scales = (const float*)d_in[2];
    const float* bias   = (const float*)d_in[3];
    float* out = (float*)d_out;

    const int N = in_sizes[2];                  // 11008
    const int K = (int)((long)in_sizes[1] / N); // 4096
    const int M = (int)((long)in_sizes[0] / K); // 4096

    const size_t need = (size_t)M * K + (size_t)N * K + (size_t)M * 4;
    const bool ok = (ws_size >= need) && (M % 128) == 0 && (N % 128) == 0 &&
                    (K % 128) == 0 && (K / 64) >= 4 && (K % 16) == 0;

    if (ok) {
        char* xq = (char*)d_ws;
        char* wq = xq + (size_t)M * K;
        float* sxbuf = (float*)(wq + (size_t)N * K);

        x_quant_i8<<<M, 256, 0, stream>>>(x, (unsigned int*)xq, sxbuf, K);
        w_to_i8<<<2048, 256, 0, stream>>>(w, (u32x4*)wq, (long)N * K / 16);

        const int nbx = N / 128;
        const int nwg = (M / 128) * nbx;
        qlinear_gemm_i8bd<<<nwg, 256, 0, stream>>>(xq, wq, sxbuf, scales, bias,
                                                   out, M, N, K, nbx);
    } else {
        dim3 grid(N / 16, M / 16), blk(16, 16);
        qlinear_fallback<<<grid, blk, 0, stream>>>(x, w, scales, bias, out, M, N, K);
    }
}

// Round 9
// 270.857 us; speedup vs baseline: 1.7087x; 1.7087x over previous
//
#include <hip/hip_runtime.h>
#include <hip/hip_bf16.h>

// ---------------------------------------------------------------------------
// QuantizedLinear: out[M,N] = (x[M,K] @ (Wq[N,K]*s[N,1]).T) + b[N]
// INT8 path (R6-validated, absmax 7.0): w -> i8 exact, x -> i8 per-row quant,
// mfma_i32_16x16x64_i8, epilogue acc*sx[m]*s[n]+b.
// Round 9: widen per-wave tile. R6-R8 established time ~= serial(LDS + MFMA);
// LDS term scales as (1/BMw + 1/BNw). Per-wave 128x64 (vs 64x64): LDS:MFMA
// ratio 0.88 vs 1.4, total LDS traffic 5.6 -> 4.2 GB. Tile 256x128, 4 waves,
// ring-3 (72 KiB -> 2 blocks/CU), ONE {vmcnt(6); s_barrier} per K-tile
// (R7-validated single-barrier WAR argument). B back in LDS (R8 showed
// B-direct exposes HBM latency on the reg-dep path: 430 us, MfmaUtil 18%).
// ---------------------------------------------------------------------------

typedef __attribute__((ext_vector_type(4))) int   i32x4;
typedef __attribute__((ext_vector_type(4))) float f32x4;
typedef __attribute__((ext_vector_type(4))) unsigned int u32x4;

// ---- w: fp32 (integer-valued) -> i8, exact ---------------------------------
__device__ static inline unsigned int pack4(int q0, int q1, int q2, int q3) {
    return (unsigned)(q0 & 255) | ((unsigned)(q1 & 255) << 8) |
           ((unsigned)(q2 & 255) << 16) | ((unsigned)(q3 & 255) << 24);
}

__global__ void w_to_i8(const float* __restrict__ in,
                        u32x4* __restrict__ out, long n16) {
    const long stride = (long)gridDim.x * blockDim.x;
    for (long i = (long)blockIdx.x * blockDim.x + threadIdx.x; i < n16; i += stride) {
        const f32x4* p = reinterpret_cast<const f32x4*>(in) + i * 4;
        u32x4 o;
#pragma unroll
        for (int v = 0; v < 4; ++v) {
            f32x4 f = p[v];
            o[v] = pack4(__float2int_rn(f[0]), __float2int_rn(f[1]),
                         __float2int_rn(f[2]), __float2int_rn(f[3]));
        }
        out[i] = o;
    }
}

// ---- x: per-row absmax quant to i8; sx[row] = rowmax/127 -------------------
__global__ void x_quant_i8(const float* __restrict__ x,
                           unsigned int* __restrict__ xq,
                           float* __restrict__ sx, int K) {
    const int row = blockIdx.x;
    const int tid = threadIdx.x;
    const float* xr = x + (size_t)row * K;
    float m = 0.f;
    for (int b = tid * 16; b < K; b += blockDim.x * 16) {
        const f32x4* p = (const f32x4*)(xr + b);
#pragma unroll
        for (int v = 0; v < 4; ++v) {
            f32x4 f = p[v];
            m = fmaxf(m, fmaxf(fmaxf(fabsf(f[0]), fabsf(f[1])),
                               fmaxf(fabsf(f[2]), fabsf(f[3]))));
        }
    }
#pragma unroll
    for (int off = 32; off; off >>= 1) m = fmaxf(m, __shfl_xor(m, off));
    __shared__ float red[8];
    if ((tid & 63) == 0) red[tid >> 6] = m;
    __syncthreads();
    const int nw = blockDim.x >> 6;
    m = red[0];
    for (int i = 1; i < nw; ++i) m = fmaxf(m, red[i]);
    const float inv = (m > 0.f) ? 127.0f / m : 0.f;
    if (tid == 0) sx[row] = m * (1.0f / 127.0f);
    for (int b = tid * 16; b < K; b += blockDim.x * 16) {
        const f32x4* p = (const f32x4*)(xr + b);
        u32x4 o;
#pragma unroll
        for (int v = 0; v < 4; ++v) {
            f32x4 f = p[v];
            int q0 = min(127, max(-127, __float2int_rn(f[0] * inv)));
            int q1 = min(127, max(-127, __float2int_rn(f[1] * inv)));
            int q2 = min(127, max(-127, __float2int_rn(f[2] * inv)));
            int q3 = min(127, max(-127, __float2int_rn(f[3] * inv)));
            o[v] = pack4(q0, q1, q2, q3);
        }
        *reinterpret_cast<u32x4*>((char*)xq + (size_t)row * K + b) = o;
    }
}

// ---------------------------------------------------------------------------
// i8 GEMM. Tile 256x128, BK=64. 256 thr = 4 waves (2M x 2N), per-wave 128x64.
// LDS 72 KiB ring-3: slot sl at sl*24576: A = 16 KiB (256 rows x 64 i8),
// B at +16384 = 8 KiB (128 rows x 64 i8). 6 gloads/thread/tile (A:4, B:2).
// Per tile: stage(t+2) | rdA(8)+rdB(4) | 32 MFMA | WAIT_VM(6) | BAR.
// Ledger: before wait, outstanding = [t+1:6, t+2:6]; vm(6) retires t+1.
// WAR: stage(t+2) hits slot of t-1, whose reads drained (lgkm before mfma)
// before BAR(t-1). Swizzle (R6-R8, 0 conflicts): phys chunk ^= (row>>1)&3,
// pre-swizzled global source, linear LDS dest (rule #21).
// ---------------------------------------------------------------------------

#define GLOAD16(src, dst) __builtin_amdgcn_global_load_lds( \
    (const __attribute__((address_space(1))) void*)(src),   \
    (__attribute__((address_space(3))) void*)(dst), 16, 0, 0)

#define FENCE() asm volatile("" ::: "memory")
#define BAR()  do { FENCE(); __builtin_amdgcn_s_barrier(); FENCE(); } while (0)
#define WAIT_VM(n) asm volatile("s_waitcnt vmcnt(" #n ")" ::: "memory")

__global__ __launch_bounds__(256, 2)
void qlinear_gemm_i8w(const char* __restrict__ A,   // [M,K] i8
                      const char* __restrict__ B,   // [N,K] i8
                      const float* __restrict__ sx, // [M] row scales of x
                      const float* __restrict__ scales,  // [N]
                      const float* __restrict__ bias,    // [N]
                      float* __restrict__ C,             // [M,N] f32
                      int M, int N, int K, int nbx) {
    __shared__ __align__(128) char smem[73728];

    const int tid  = threadIdx.x;
    const int lane = tid & 63;
    const int wid  = tid >> 6;
    const int mslab = (wid >> 1) * 128;  // 2 M-slabs of 128
    const int nslab = (wid & 1) * 64;    // 2 N-slabs of 64

    // T1: bijective XCD swizzle (m204); bcol-fastest (A panel L2-resident)
    const int nwg = gridDim.x;
    const int q = nwg >> 3, r = nwg & 7;
    const int xcd = blockIdx.x & 7, boff_ = blockIdx.x >> 3;
    const int swz = (xcd < r ? xcd * (q + 1) : r * (q + 1) + (xcd - r) * q) + boff_;
    const int bcol = swz % nbx;
    const int brow = swz / nbx;

    const char* Ag = A + (size_t)brow * 256 * K;
    const char* Bg = B + (size_t)bcol * 128 * K;

    // ---- staging: A 1024 chunks (4/thread), B 512 chunks (2/thread).
    // chunk c -> row c>>2, phys slot c&3; global src chunk = phys ^ ((row>>1)&3).
    size_t ga[4], gb[2];
#pragma unroll
    for (int j = 0; j < 4; ++j) {
        const int c = tid + j * 256, rr = c >> 2, pp = c & 3;
        ga[j] = (size_t)rr * K + ((pp ^ ((rr >> 1) & 3)) << 4);
    }
#pragma unroll
    for (int j = 0; j < 2; ++j) {
        const int c = tid + j * 256, rr = c >> 2, pp = c & 3;
        gb[j] = (size_t)rr * K + ((pp ^ ((rr >> 1) & 3)) << 4);
    }

    auto stageT = [&](int sl, int t) {
        const size_t ko = (size_t)t * 64;
        char* base = smem + sl * 24576;
#pragma unroll
        for (int j = 0; j < 4; ++j)
            GLOAD16(Ag + ga[j] + ko, base + (tid + j * 256) * 16);
#pragma unroll
        for (int j = 0; j < 2; ++j)
            GLOAD16(Bg + gb[j] + ko, base + 16384 + (tid + j * 256) * 16);
    };

    // ---- reads: row = slab + f*16 + (lane&15); phys chunk =
    // (lane>>4) ^ ((lane>>1)&3)  (row swizzle bits reduce to lane bits 1-2).
    const int cph  = ((lane >> 4) ^ ((lane >> 1) & 3)) << 4;
    const int aoff = (mslab + (lane & 15)) * 64 + cph;
    const int boff = (nslab + (lane & 15)) * 64 + cph;

    i32x4 acc[8][4] = {};
    i32x4 af[8], bf[4];

    auto rdAB = [&](int sl) {
        const char* pa = smem + sl * 24576 + aoff;
#pragma unroll
        for (int mi = 0; mi < 8; ++mi) af[mi] = *(const i32x4*)(pa + mi * 1024);
        const char* pb = smem + sl * 24576 + 16384 + boff;
#pragma unroll
        for (int ni = 0; ni < 4; ++ni) bf[ni] = *(const i32x4*)(pb + ni * 1024);
    };
    auto mfma32 = [&]() {
        __builtin_amdgcn_s_setprio(1);
#pragma unroll
        for (int mi = 0; mi < 8; ++mi)
#pragma unroll
            for (int ni = 0; ni < 4; ++ni)
                acc[mi][ni] = __builtin_amdgcn_mfma_i32_16x16x64_i8(
                    af[mi], bf[ni], acc[mi][ni], 0, 0, 0);
        __builtin_amdgcn_s_setprio(0);
    };

    const int NT = K / 64;   // >= 4 (dispatch guard)

    // ---- prologue: stage tiles 0,1 (12 gloads); tile0 landed after vm(6) ----
    stageT(0, 0); stageT(1, 1);
    WAIT_VM(6); BAR();

    // ---- main loop: ONE {vmcnt(6); barrier} per tile ----
    int sl = 0;
    for (int t = 0; t < NT - 2; ++t) {
        int s2 = sl + 2; if (s2 >= 3) s2 -= 3;
        stageT(s2, t + 2);
        rdAB(sl);
        mfma32();
        WAIT_VM(6);        // retire tile t+1's 6 gloads; keep t+2's in flight
        BAR();
        sl = (sl == 2) ? 0 : sl + 1;
    }
    // t = NT-2
    rdAB(sl);
    mfma32();
    WAIT_VM(0);            // last tile landed
    BAR();
    sl = (sl == 2) ? 0 : sl + 1;
    // t = NT-1
    rdAB(sl);
    mfma32();

    // ---- epilogue: C/D layout col=lane&15, row=(lane>>4)*4+j ----
    const int lc  = lane & 15;
    const int lr4 = (lane >> 4) * 4;
    float sarr[4], barr[4];
#pragma unroll
    for (int ni = 0; ni < 4; ++ni) {
        const int n = bcol * 128 + nslab + ni * 16 + lc;
        sarr[ni] = scales[n];
        barr[ni] = bias[n];
    }
#pragma unroll
    for (int mi = 0; mi < 8; ++mi) {
        const int mb = brow * 256 + mslab + mi * 16 + lr4;
        const f32x4 sxv = *(const f32x4*)&sx[mb];
#pragma unroll
        for (int j = 0; j < 4; ++j) {
            const size_t rowoff = (size_t)(mb + j) * N;
            const float sm = sxv[j];
#pragma unroll
            for (int ni = 0; ni < 4; ++ni) {
                const int n = bcol * 128 + nslab + ni * 16 + lc;
                C[rowoff + n] = fmaf((float)acc[mi][ni][j], sm * sarr[ni], barr[ni]);
            }
        }
    }
}

// ---- Fallback: plain fp32 tiled GEMM, correctness insurance ----------------
__global__ void qlinear_fallback(const float* __restrict__ A,
                                 const float* __restrict__ B,
                                 const float* __restrict__ scales,
                                 const float* __restrict__ bias,
                                 float* __restrict__ C, int M, int N, int K) {
    __shared__ float As[16][17], Bs[16][17];
    const int tx = threadIdx.x, ty = threadIdx.y;
    const int row = blockIdx.y * 16 + ty;
    const int col = blockIdx.x * 16 + tx;
    float acc = 0.f;
    for (int k0 = 0; k0 < K; k0 += 16) {
        As[ty][tx] = A[(long)row * K + k0 + tx];
        Bs[ty][tx] = B[(long)(blockIdx.x * 16 + ty) * K + k0 + tx];
        __syncthreads();
#pragma unroll
        for (int kk = 0; kk < 16; ++kk) acc += As[ty][kk] * Bs[tx][kk];
        __syncthreads();
    }
    C[(long)row * N + col] = fmaf(acc, scales[col], bias[col]);
}

extern "C" void kernel_launch(void* const* d_in, const int* in_sizes, int n_in,
                              void* d_out, int out_size, void* d_ws, size_t ws_size,
                              hipStream_t stream) {
    const float* x      = (const float*)d_in[0];
    const float* w      = (const float*)d_in[1];
    const float* scales = (const float*)d_in[2];
    const float* bias   = (const float*)d_in[3];
    float* out = (float*)d_out;

    const int N = in_sizes[2];                  // 11008
    const int K = (int)((long)in_sizes[1] / N); // 4096
    const int M = (int)((long)in_sizes[0] / K); // 4096

    const size_t need = (size_t)M * K + (size_t)N * K + (size_t)M * 4;
    const bool ok = (ws_size >= need) && (M % 256) == 0 && (N % 128) == 0 &&
                    (K % 64) == 0 && (K / 64) >= 4 && (K % 16) == 0;

    if (ok) {
        char* xq = (char*)d_ws;
        char* wq = xq + (size_t)M * K;
        float* sxbuf = (float*)(wq + (size_t)N * K);

        x_quant_i8<<<M, 256, 0, stream>>>(x, (unsigned int*)xq, sxbuf, K);
        w_to_i8<<<2048, 256, 0, stream>>>(w, (u32x4*)wq, (long)N * K / 16);

        const int nbx = N / 128;
        const int nwg = (M / 256) * nbx;
        qlinear_gemm_i8w<<<nwg, 256, 0, stream>>>(xq, wq, sxbuf, scales, bias,
                                                  out, M, N, K, nbx);
    } else {
        dim3 grid(N / 16, M / 16), blk(16, 16);
        qlinear_fallback<<<grid, blk, 0, stream>>>(x, w, scales, bias, out, M, N, K);
    }
}

// Round 10
// 266.191 us; speedup vs baseline: 1.7387x; 1.0175x over previous
//
#include <hip/hip_runtime.h>
#include <hip/hip_bf16.h>

// ---------------------------------------------------------------------------
// QuantizedLinear: out[M,N] = (x[M,K] @ (Wq[N,K]*s[N,1]).T) + b[N]
// INT8 path (R6+): w -> i8 exact, x -> i8 per-row quant (absmax 7.0 < 15.36),
// mfma_i32_16x16x64_i8, epilogue acc*sx[m]*s[n]+b.
// Round 10: m201 8-phase port (the R2 structure, this time with the VERIFIED
// 0-conflict swizzle — R2's failure was conflicts, confounded with structure).
// 256x256 tile, 8 waves (2Mx4N, per-wave 128x64), ring-3 LDS 96 KiB, lead-2
// staging, 4 phases/K-tile = per-wave output quadrants, reg-cached frags
// (reads 6/4/2/0 per phase), per phase {reads | stage-half | BAR | lgkm0+SB |
// setprio MFMA | BAR}, ONE WAIT_VM(4) at P4.
// ---------------------------------------------------------------------------

typedef __attribute__((ext_vector_type(4))) int   i32x4;
typedef __attribute__((ext_vector_type(4))) float f32x4;
typedef __attribute__((ext_vector_type(4))) unsigned int u32x4;

// ---- w: fp32 (integer-valued) -> i8, exact ---------------------------------
__device__ static inline unsigned int pack4(int q0, int q1, int q2, int q3) {
    return (unsigned)(q0 & 255) | ((unsigned)(q1 & 255) << 8) |
           ((unsigned)(q2 & 255) << 16) | ((unsigned)(q3 & 255) << 24);
}

__global__ void w_to_i8(const float* __restrict__ in,
                        u32x4* __restrict__ out, long n16) {
    const long stride = (long)gridDim.x * blockDim.x;
    for (long i = (long)blockIdx.x * blockDim.x + threadIdx.x; i < n16; i += stride) {
        const f32x4* p = reinterpret_cast<const f32x4*>(in) + i * 4;
        u32x4 o;
#pragma unroll
        for (int v = 0; v < 4; ++v) {
            f32x4 f = p[v];
            o[v] = pack4(__float2int_rn(f[0]), __float2int_rn(f[1]),
                         __float2int_rn(f[2]), __float2int_rn(f[3]));
        }
        out[i] = o;
    }
}

// ---- x: per-row absmax quant to i8; sx[row] = rowmax/127 -------------------
__global__ void x_quant_i8(const float* __restrict__ x,
                           unsigned int* __restrict__ xq,
                           float* __restrict__ sx, int K) {
    const int row = blockIdx.x;
    const int tid = threadIdx.x;
    const float* xr = x + (size_t)row * K;
    float m = 0.f;
    for (int b = tid * 16; b < K; b += blockDim.x * 16) {
        const f32x4* p = (const f32x4*)(xr + b);
#pragma unroll
        for (int v = 0; v < 4; ++v) {
            f32x4 f = p[v];
            m = fmaxf(m, fmaxf(fmaxf(fabsf(f[0]), fabsf(f[1])),
                               fmaxf(fabsf(f[2]), fabsf(f[3]))));
        }
    }
#pragma unroll
    for (int off = 32; off; off >>= 1) m = fmaxf(m, __shfl_xor(m, off));
    __shared__ float red[8];
    if ((tid & 63) == 0) red[tid >> 6] = m;
    __syncthreads();
    const int nw = blockDim.x >> 6;
    m = red[0];
    for (int i = 1; i < nw; ++i) m = fmaxf(m, red[i]);
    const float inv = (m > 0.f) ? 127.0f / m : 0.f;
    if (tid == 0) sx[row] = m * (1.0f / 127.0f);
    for (int b = tid * 16; b < K; b += blockDim.x * 16) {
        const f32x4* p = (const f32x4*)(xr + b);
        u32x4 o;
#pragma unroll
        for (int v = 0; v < 4; ++v) {
            f32x4 f = p[v];
            int q0 = min(127, max(-127, __float2int_rn(f[0] * inv)));
            int q1 = min(127, max(-127, __float2int_rn(f[1] * inv)));
            int q2 = min(127, max(-127, __float2int_rn(f[2] * inv)));
            int q3 = min(127, max(-127, __float2int_rn(f[3] * inv)));
            o[v] = pack4(q0, q1, q2, q3);
        }
        *reinterpret_cast<u32x4*>((char*)xq + (size_t)row * K + b) = o;
    }
}

// ---------------------------------------------------------------------------
// i8 GEMM, 8-phase. Tile 256x256, BK=64. 512 thr = 8 waves (2M x 4N),
// per-wave 128x64 (acc[8][4] i32x4). LDS 96 KiB:
//   A rings: r*16384, 256 rows x 64 B;  B rings: 49152 + r*16384.
// Staging lead-2 into ring (t+2)%3, one half-tile (1 gload/thread) per phase:
//   P1: A-half0, P2: B-half0, P3: A-half1, P4: B-half1; WAIT_VM(4) at P4
//   retires tile t+1's 4 stages (ledger verified), keeps t+2's in flight.
// Reads (from ring t%3, all landed): P1 a0(4)+b0(2), P2 a1(4), P3 b1(2).
// Swizzle (R6-R9, 0 conflicts): phys 16B chunk ^= (row>>1)&3; pre-swizzled
// global source, linear LDS dest (rule #21).
// ---------------------------------------------------------------------------

#define GLOAD16(src, dst) __builtin_amdgcn_global_load_lds( \
    (const __attribute__((address_space(1))) void*)(src),   \
    (__attribute__((address_space(3))) void*)(dst), 16, 0, 0)

#define FENCE() asm volatile("" ::: "memory")
#define BAR()  do { FENCE(); __builtin_amdgcn_s_barrier(); FENCE(); } while (0)
#define WAIT_VM(n) asm volatile("s_waitcnt vmcnt(" #n ")" ::: "memory")
#define WAIT_LGKM0() asm volatile("s_waitcnt lgkmcnt(0)" ::: "memory")
#define SCHED0() __builtin_amdgcn_sched_barrier(0)

__global__ __launch_bounds__(512, 2)
void qlinear_gemm_i8p8(const char* __restrict__ A,   // [M,K] i8
                       const char* __restrict__ B,   // [N,K] i8
                       const float* __restrict__ sx, // [M]
                       const float* __restrict__ scales,  // [N]
                       const float* __restrict__ bias,    // [N]
                       float* __restrict__ C,             // [M,N] f32
                       int M, int N, int K, int nbx) {
    __shared__ __align__(128) char smem[98304];

    const int tid  = threadIdx.x;
    const int lane = tid & 63;
    const int wid  = tid >> 6;
    const int wr   = wid >> 2;   // 0..1 -> 128-row slab
    const int wc   = wid & 3;    // 0..3 -> 64-col slab

    // T1: bijective XCD swizzle (m204); bcol-fastest
    const int nwg = gridDim.x;
    const int q = nwg >> 3, r = nwg & 7;
    const int xcd = blockIdx.x & 7, boff_ = blockIdx.x >> 3;
    const int swz = (xcd < r ? xcd * (q + 1) : r * (q + 1) + (xcd - r) * q) + boff_;
    const int bcol = swz % nbx;
    const int brow = swz / nbx;

    const char* Ag = A + (size_t)brow * 256 * K;
    const char* Bg = B + (size_t)bcol * 256 * K;

    // ---- staging geometry: thread tid -> row tid>>2 (of 128 in a half),
    // phys 16B slot tid&3; source k-chunk = (tid&3) ^ ((tid>>3)&3).
    const int srow = tid >> 2;
    const size_t gsrc = ((size_t)srow * K) + (((tid & 3) ^ ((tid >> 3) & 3)) << 4);
    const int ldst = tid * 16;

    auto stageH = [&](int mat, int h, int rs, int t) {
        const char* G = (mat ? Bg : Ag) + (size_t)h * 128 * K;
        GLOAD16(G + gsrc + (size_t)t * 64,
                smem + mat * 49152 + rs * 16384 + h * 8192 + ldst);
    };

    // ---- read geometry: row -> phys chunk (lane>>4) ^ ((lane>>1)&3) ----
    const int cph  = ((lane >> 4) ^ ((lane >> 1) & 3)) << 4;
    const int arow = (wr * 128 + (lane & 15)) * 64 + cph;   // + mh*64*64 + i*16*64
    const int brow_ = (wc * 64 + (lane & 15)) * 64 + cph;   // + nh*32*64 + n*16*64

    i32x4 acc[8][4] = {};
    i32x4 a0[4], a1[4], b0[2], b1[2];

    auto rdA = [&](int rg, int mh, i32x4 (&d)[4]) {
        const char* p = smem + rg * 16384 + arow + mh * 4096;
#pragma unroll
        for (int i = 0; i < 4; ++i) d[i] = *(const i32x4*)(p + i * 1024);
    };
    auto rdB = [&](int rg, int nh, i32x4 (&d)[2]) {
        const char* p = smem + 49152 + rg * 16384 + brow_ + nh * 2048;
#pragma unroll
        for (int n = 0; n < 2; ++n) d[n] = *(const i32x4*)(p + n * 1024);
    };
    auto mfma8 = [&](const i32x4 (&a)[4], const i32x4 (&b)[2], int qm, int qn) {
        __builtin_amdgcn_s_setprio(1);
#pragma unroll
        for (int i = 0; i < 4; ++i)
#pragma unroll
            for (int n = 0; n < 2; ++n)
                acc[qm * 4 + i][qn * 2 + n] = __builtin_amdgcn_mfma_i32_16x16x64_i8(
                    a[i], b[n], acc[qm * 4 + i][qn * 2 + n], 0, 0, 0);
        __builtin_amdgcn_s_setprio(0);
    };

    const int NT = K / 64;   // >= 4 (dispatch guard)

    // ---- prologue: stage tiles 0 (ring 0) and 1 (ring 1); tile0 landed ----
    stageH(0, 0, 0, 0); stageH(1, 0, 0, 0); stageH(0, 1, 0, 0); stageH(1, 1, 0, 0);
    stageH(0, 0, 1, 1); stageH(1, 0, 1, 1); stageH(0, 1, 1, 1); stageH(1, 1, 1, 1);
    WAIT_VM(4); BAR();

    // ---- main loop ----
    int rg = 0;                       // ring of tile t
    for (int t = 0; t < NT - 2; ++t) {
        int rs = rg + 2; if (rs >= 3) rs -= 3;   // ring of tile t+2
        // P1
        rdA(rg, 0, a0); rdB(rg, 0, b0);
        stageH(0, 0, rs, t + 2);
        BAR(); WAIT_LGKM0(); SCHED0();
        mfma8(a0, b0, 0, 0);
        BAR();
        // P2
        rdA(rg, 1, a1);
        stageH(1, 0, rs, t + 2);
        BAR(); WAIT_LGKM0(); SCHED0();
        mfma8(a1, b0, 1, 0);
        BAR();
        // P3
        rdB(rg, 1, b1);
        stageH(0, 1, rs, t + 2);
        BAR(); WAIT_LGKM0(); SCHED0();
        mfma8(a0, b1, 0, 1);
        BAR();
        // P4
        stageH(1, 1, rs, t + 2);
        mfma8(a1, b1, 1, 1);
        WAIT_VM(4);                   // retire tile t+1's 4 stages
        BAR();
        rg = (rg == 2) ? 0 : rg + 1;
    }
    // ---- t = NT-2 (no staging; drain last tile's stages at P4) ----
    rdA(rg, 0, a0); rdB(rg, 0, b0);
    BAR(); WAIT_LGKM0(); SCHED0();
    mfma8(a0, b0, 0, 0);
    BAR();
    rdA(rg, 1, a1);
    BAR(); WAIT_LGKM0(); SCHED0();
    mfma8(a1, b0, 1, 0);
    BAR();
    rdB(rg, 1, b1);
    BAR(); WAIT_LGKM0(); SCHED0();
    mfma8(a0, b1, 0, 1);
    BAR();
    mfma8(a1, b1, 1, 1);
    WAIT_VM(0);
    BAR();
    rg = (rg == 2) ? 0 : rg + 1;
    // ---- t = NT-1 (pure compute) ----
    rdA(rg, 0, a0); rdB(rg, 0, b0);
    WAIT_LGKM0(); SCHED0();
    mfma8(a0, b0, 0, 0);
    rdA(rg, 1, a1);
    WAIT_LGKM0(); SCHED0();
    mfma8(a1, b0, 1, 0);
    rdB(rg, 1, b1);
    WAIT_LGKM0(); SCHED0();
    mfma8(a0, b1, 0, 1);
    mfma8(a1, b1, 1, 1);

    // ---- epilogue: row = wr*128 + (mi>>2)*64 + (mi&3)*16 + (lane>>4)*4+j
    //               col = wc*64  + (ni>>1)*32 + (ni&1)*16 + (lane&15)
    const int lc  = lane & 15;
    const int lr4 = (lane >> 4) * 4;
    float sarr[4], barr[4];
#pragma unroll
    for (int ni = 0; ni < 4; ++ni) {
        const int n = bcol * 256 + wc * 64 + (ni >> 1) * 32 + (ni & 1) * 16 + lc;
        sarr[ni] = scales[n];
        barr[ni] = bias[n];
    }
#pragma unroll
    for (int mi = 0; mi < 8; ++mi) {
        const int mb = brow * 256 + wr * 128 + (mi >> 2) * 64 + (mi & 3) * 16 + lr4;
#pragma unroll
        for (int j = 0; j < 4; ++j) {
            const size_t rowoff = (size_t)(mb + j) * N;
            const float sm = sx[mb + j];
#pragma unroll
            for (int ni = 0; ni < 4; ++ni) {
                const int n = bcol * 256 + wc * 64 + (ni >> 1) * 32 + (ni & 1) * 16 + lc;
                C[rowoff + n] = fmaf((float)acc[mi][ni][j], sm * sarr[ni], barr[ni]);
            }
        }
    }
}

// ---- Fallback: plain fp32 tiled GEMM, correctness insurance ----------------
__global__ void qlinear_fallback(const float* __restrict__ A,
                                 const float* __restrict__ B,
                                 const float* __restrict__ scales,
                                 const float* __restrict__ bias,
                                 float* __restrict__ C, int M, int N, int K) {
    __shared__ float As[16][17], Bs[16][17];
    const int tx = threadIdx.x, ty = threadIdx.y;
    const int row = blockIdx.y * 16 + ty;
    const int col = blockIdx.x * 16 + tx;
    float acc = 0.f;
    for (int k0 = 0; k0 < K; k0 += 16) {
        As[ty][tx] = A[(long)row * K + k0 + tx];
        Bs[ty][tx] = B[(long)(blockIdx.x * 16 + ty) * K + k0 + tx];
        __syncthreads();
#pragma unroll
        for (int kk = 0; kk < 16; ++kk) acc += As[ty][kk] * Bs[tx][kk];
        __syncthreads();
    }
    C[(long)row * N + col] = fmaf(acc, scales[col], bias[col]);
}

extern "C" void kernel_launch(void* const* d_in, const int* in_sizes, int n_in,
                              void* d_out, int out_size, void* d_ws, size_t ws_size,
                              hipStream_t stream) {
    const float* x      = (const float*)d_in[0];
    const float* w      = (const float*)d_in[1];
    const float* scales = (const float*)d_in[2];
    const float* bias   = (const float*)d_in[3];
    float* out = (float*)d_out;

    const int N = in_sizes[2];                  // 11008
    const int K = (int)((long)in_sizes[1] / N); // 4096
    const int M = (int)((long)in_sizes[0] / K); // 4096

    const size_t need = (size_t)M * K + (size_t)N * K + (size_t)M * 4;
    const bool ok = (ws_size >= need) && (M % 256) == 0 && (N % 256) == 0 &&
                    (K % 64) == 0 && (K / 64) >= 4 && (K % 16) == 0;

    if (ok) {
        char* xq = (char*)d_ws;
        char* wq = xq + (size_t)M * K;
        float* sxbuf = (float*)(wq + (size_t)N * K);

        x_quant_i8<<<M, 256, 0, stream>>>(x, (unsigned int*)xq, sxbuf, K);
        w_to_i8<<<2048, 256, 0, stream>>>(w, (u32x4*)wq, (long)N * K / 16);

        const int nbx = N / 256;
        const int nwg = (M / 256) * nbx;
        qlinear_gemm_i8p8<<<nwg, 512, 0, stream>>>(xq, wq, sxbuf, scales, bias,
                                                   out, M, N, K, nbx);
    } else {
        dim3 grid(N / 16, M / 16), blk(16, 16);
        qlinear_fallback<<<grid, blk, 0, stream>>>(x, w, scales, bias, out, M, N, K);
    }
}

// Round 11
// 253.778 us; speedup vs baseline: 1.8237x; 1.0489x over previous
//
#include <hip/hip_runtime.h>
#include <hip/hip_bf16.h>

// ---------------------------------------------------------------------------
// QuantizedLinear: out[M,N] = (x[M,K] @ (Wq[N,K]*s[N,1]).T) + b[N]
// INT8 path (R6+, absmax 7.0): w -> i8 exact, x -> i8 per-row quant,
// mfma_i32_16x16x64_i8, epilogue acc*sx[m]*s[n]+b.
// Round 11: BK=128 -> byte-exact m201 geometry. 256x256, 8 waves (2Mx4N,
// per-wave 128x64), LDS 128 KiB dbuf-2. Per tile: 4 phases x 16 MFMA
// (quadrant x kk0,1), reads 12/8/4/0, 1 half-tile stage (2 gloads)/phase,
// lgkm(8) pace at P1, ONE vmcnt(6) at P4 (lead = 3 half-tiles).
// Half-tiles on quadrant-union rows (A: bit6, B: bit5) so each stage's WAR
// window is closed by the prior phase's lgkm0+barrier (ledger verified).
// ---------------------------------------------------------------------------

typedef __attribute__((ext_vector_type(4))) int   i32x4;
typedef __attribute__((ext_vector_type(4))) float f32x4;
typedef __attribute__((ext_vector_type(4))) unsigned int u32x4;

// ---- w: fp32 (integer-valued) -> i8, exact ---------------------------------
__device__ static inline unsigned int pack4(int q0, int q1, int q2, int q3) {
    return (unsigned)(q0 & 255) | ((unsigned)(q1 & 255) << 8) |
           ((unsigned)(q2 & 255) << 16) | ((unsigned)(q3 & 255) << 24);
}

__global__ void w_to_i8(const float* __restrict__ in,
                        u32x4* __restrict__ out, long n16) {
    const long stride = (long)gridDim.x * blockDim.x;
    for (long i = (long)blockIdx.x * blockDim.x + threadIdx.x; i < n16; i += stride) {
        const f32x4* p = reinterpret_cast<const f32x4*>(in) + i * 4;
        u32x4 o;
#pragma unroll
        for (int v = 0; v < 4; ++v) {
            f32x4 f = p[v];
            o[v] = pack4(__float2int_rn(f[0]), __float2int_rn(f[1]),
                         __float2int_rn(f[2]), __float2int_rn(f[3]));
        }
        out[i] = o;
    }
}

// ---- x: per-row absmax quant to i8; sx[row] = rowmax/127 -------------------
__global__ void x_quant_i8(const float* __restrict__ x,
                           unsigned int* __restrict__ xq,
                           float* __restrict__ sx, int K) {
    const int row = blockIdx.x;
    const int tid = threadIdx.x;
    const float* xr = x + (size_t)row * K;
    float m = 0.f;
    for (int b = tid * 16; b < K; b += blockDim.x * 16) {
        const f32x4* p = (const f32x4*)(xr + b);
#pragma unroll
        for (int v = 0; v < 4; ++v) {
            f32x4 f = p[v];
            m = fmaxf(m, fmaxf(fmaxf(fabsf(f[0]), fabsf(f[1])),
                               fmaxf(fabsf(f[2]), fabsf(f[3]))));
        }
    }
#pragma unroll
    for (int off = 32; off; off >>= 1) m = fmaxf(m, __shfl_xor(m, off));
    __shared__ float red[8];
    if ((tid & 63) == 0) red[tid >> 6] = m;
    __syncthreads();
    const int nw = blockDim.x >> 6;
    m = red[0];
    for (int i = 1; i < nw; ++i) m = fmaxf(m, red[i]);
    const float inv = (m > 0.f) ? 127.0f / m : 0.f;
    if (tid == 0) sx[row] = m * (1.0f / 127.0f);
    for (int b = tid * 16; b < K; b += blockDim.x * 16) {
        const f32x4* p = (const f32x4*)(xr + b);
        u32x4 o;
#pragma unroll
        for (int v = 0; v < 4; ++v) {
            f32x4 f = p[v];
            int q0 = min(127, max(-127, __float2int_rn(f[0] * inv)));
            int q1 = min(127, max(-127, __float2int_rn(f[1] * inv)));
            int q2 = min(127, max(-127, __float2int_rn(f[2] * inv)));
            int q3 = min(127, max(-127, __float2int_rn(f[3] * inv)));
            o[v] = pack4(q0, q1, q2, q3);
        }
        *reinterpret_cast<u32x4*>((char*)xq + (size_t)row * K + b) = o;
    }
}

// ---------------------------------------------------------------------------
// i8 GEMM, BK=128. LDS: A rings r*32768 (2 halves of 16 KiB: [h][rlocal][128B
// rows of 8 x 16B chunks]); B rings 65536 + r*32768 (same shape).
// A-half h = tile rows with bit6==h (union of per-wave mh quadrants);
// B-half h = tile rows with bit5==h.
// Swizzle (R4 algebra, measured 0 conflicts): phys chunk = logical ^ (row&7);
// pre-swizzled global source, linear LDS dest (rule #21).
// ---------------------------------------------------------------------------

#define GLOAD16(src, dst) __builtin_amdgcn_global_load_lds( \
    (const __attribute__((address_space(1))) void*)(src),   \
    (__attribute__((address_space(3))) void*)(dst), 16, 0, 0)

#define FENCE() asm volatile("" ::: "memory")
#define BAR()  do { FENCE(); __builtin_amdgcn_s_barrier(); FENCE(); } while (0)
#define WAIT_VM(n) asm volatile("s_waitcnt vmcnt(" #n ")" ::: "memory")
#define WAIT_LGKM0() asm volatile("s_waitcnt lgkmcnt(0)" ::: "memory")
#define PACE_LGKM(n) asm volatile("s_waitcnt lgkmcnt(" #n ")" ::: "memory")
#define SCHED0() __builtin_amdgcn_sched_barrier(0)

__global__ __launch_bounds__(512, 2)
void qlinear_gemm_i8k128(const char* __restrict__ A,   // [M,K] i8
                         const char* __restrict__ B,   // [N,K] i8
                         const float* __restrict__ sx, // [M]
                         const float* __restrict__ scales,  // [N]
                         const float* __restrict__ bias,    // [N]
                         float* __restrict__ C,             // [M,N] f32
                         int M, int N, int K, int nbx) {
    __shared__ __align__(128) char smem[131072];

    const int tid  = threadIdx.x;
    const int lane = tid & 63;
    const int wid  = tid >> 6;
    const int wr   = wid >> 2;   // 0..1 -> 128-row slab
    const int wc   = wid & 3;    // 0..3 -> 64-col slab

    // T1: bijective XCD swizzle (m204)
    const int nwg = gridDim.x;
    const int q = nwg >> 3, r = nwg & 7;
    const int xcd = blockIdx.x & 7, boff_ = blockIdx.x >> 3;
    const int swz = (xcd < r ? xcd * (q + 1) : r * (q + 1) + (xcd - r) * q) + boff_;
    const int bcol = swz % nbx;
    const int brow = swz / nbx;

    const char* Ag = A + (size_t)brow * 256 * K;
    const char* Bg = B + (size_t)bcol * 256 * K;

    // ---- staging source offsets (h-independent parts), 2 chunks/thread ----
    // chunk c in a 16 KiB half: rlocal = c>>3, j = c&7; src chunk = j^(rl&7).
    size_t sA[2], sB[2];
#pragma unroll
    for (int g = 0; g < 2; ++g) {
        const int c = tid + g * 512, rl = c >> 3, j = c & 7;
        const int rowA = ((rl >> 6) << 7) + (rl & 63);   // + h*64 at use
        const int rowB = ((rl >> 5) << 6) + (rl & 31);   // + h*32 at use
        sA[g] = (size_t)rowA * K + ((j ^ (rl & 7)) << 4);
        sB[g] = (size_t)rowB * K + ((j ^ (rl & 7)) << 4);
    }
    const int ld0 = tid * 16;   // dest for g=0; g=1 at +8192

    auto stageA = [&](int rg, int h, int t) {
        const char* G = Ag + (size_t)h * 64 * K + (size_t)t * 128;
        char* base = smem + rg * 32768 + h * 16384;
        GLOAD16(G + sA[0], base + ld0);
        GLOAD16(G + sA[1], base + ld0 + 8192);
    };
    auto stageB = [&](int rg, int h, int t) {
        const char* G = Bg + (size_t)h * 32 * K + (size_t)t * 128;
        char* base = smem + 65536 + rg * 32768 + h * 16384;
        GLOAD16(G + sB[0], base + ld0);
        GLOAD16(G + sB[1], base + ld0 + 8192);
    };

    // ---- read geometry ----
    const int px0 = (((lane >> 4) ^ (lane & 7)) << 4);        // kk=0
    const int px1 = (((4 + (lane >> 4)) ^ (lane & 7)) << 4);  // kk=1
    const int arow = (wr * 64 + (lane & 15)) * 128;  // within a half: +i*2048
    const int brw  = (wc * 32 + (lane & 15)) * 128;  // within a half: +n*2048

    i32x4 acc[8][4] = {};
    i32x4 a0[8], a1[8], b0[4], b1[4];

    auto rdA = [&](int rg, int mh, i32x4 (&d)[8]) {   // 8 ds_read_b128
        const char* p = smem + rg * 32768 + mh * 16384 + arow;
#pragma unroll
        for (int i = 0; i < 4; ++i) {
            d[i * 2]     = *(const i32x4*)(p + i * 2048 + px0);
            d[i * 2 + 1] = *(const i32x4*)(p + i * 2048 + px1);
        }
    };
    auto rdB = [&](int rg, int nh, i32x4 (&d)[4]) {   // 4 ds_read_b128
        const char* p = smem + 65536 + rg * 32768 + nh * 16384 + brw;
#pragma unroll
        for (int n = 0; n < 2; ++n) {
            d[n * 2]     = *(const i32x4*)(p + n * 2048 + px0);
            d[n * 2 + 1] = *(const i32x4*)(p + n * 2048 + px1);
        }
    };
    auto mfma16 = [&](const i32x4 (&a)[8], const i32x4 (&b)[4], int mh, int nh) {
        __builtin_amdgcn_s_setprio(1);
#pragma unroll
        for (int i = 0; i < 4; ++i)
#pragma unroll
            for (int n = 0; n < 2; ++n) {
                i32x4& ac = acc[mh * 4 + i][nh * 2 + n];
                ac = __builtin_amdgcn_mfma_i32_16x16x64_i8(a[i * 2], b[n * 2], ac, 0, 0, 0);
                ac = __builtin_amdgcn_mfma_i32_16x16x64_i8(a[i * 2 + 1], b[n * 2 + 1], ac, 0, 0, 0);
            }
        __builtin_amdgcn_s_setprio(0);
    };

    const int NT = K / 128;   // >= 3 (dispatch guard)

    // ---- prologue: tile0 all 4 half-tiles (8), tile1 A0,B0,A1 (+6) ----
    stageA(0, 0, 0); stageB(0, 0, 0); stageA(0, 1, 0); stageB(0, 1, 0);
    stageA(1, 0, 1); stageB(1, 0, 1); stageA(1, 1, 1);
    WAIT_VM(6); BAR();   // tile0 landed; 3 half-tiles of tile1 in flight

    // ---- main loop (invariant at top: t landed; t+1 A0,B0,A1 in flight) ----
    for (int t = 0; t < NT - 2; ++t) {
        const int c = t & 1, o = c ^ 1;
        // P1: quad(0,0)
        rdA(c, 0, a0); rdB(c, 0, b0);
        stageB(o, 1, t + 1);            // in flight 8
        PACE_LGKM(8);
        BAR(); WAIT_LGKM0(); SCHED0();
        mfma16(a0, b0, 0, 0);
        BAR();
        // P2: quad(1,0) | stage t+2:A0 into ring c (A-h0 read-drained at P1)
        rdA(c, 1, a1);
        stageA(c, 0, t + 2);            // 10
        BAR(); WAIT_LGKM0(); SCHED0();
        mfma16(a1, b0, 1, 0);
        BAR();
        // P3: quad(0,1) | stage t+2:B0 (B-h0 drained at P1)
        rdB(c, 1, b1);
        stageB(c, 0, t + 2);            // 12
        BAR(); WAIT_LGKM0(); SCHED0();
        mfma16(a0, b1, 0, 1);
        BAR();
        // P4: quad(1,1) | stage t+2:A1 (A-h1 drained at P2) | vm(6)
        stageA(c, 1, t + 2);            // 14
        mfma16(a1, b1, 1, 1);
        WAIT_VM(6);                     // retires tile t+1's 8 loads exactly
        BAR();
    }
    // ---- t = NT-2: stage only (NT-1, B1); drain at P4 ----
    {
        const int c = (NT - 2) & 1, o = c ^ 1;
        rdA(c, 0, a0); rdB(c, 0, b0);
        stageB(o, 1, NT - 1);           // tile NT-1 fully issued (8)
        PACE_LGKM(8);
        BAR(); WAIT_LGKM0(); SCHED0();
        mfma16(a0, b0, 0, 0);
        BAR();
        rdA(c, 1, a1);
        BAR(); WAIT_LGKM0(); SCHED0();
        mfma16(a1, b0, 1, 0);
        BAR();
        rdB(c, 1, b1);
        BAR(); WAIT_LGKM0(); SCHED0();
        mfma16(a0, b1, 0, 1);
        BAR();
        mfma16(a1, b1, 1, 1);
        WAIT_VM(0);                     // tile NT-1 landed
        BAR();
    }
    // ---- t = NT-1: pure compute ----
    {
        const int c = (NT - 1) & 1;
        rdA(c, 0, a0); rdB(c, 0, b0);
        WAIT_LGKM0(); SCHED0();
        mfma16(a0, b0, 0, 0);
        rdA(c, 1, a1);
        WAIT_LGKM0(); SCHED0();
        mfma16(a1, b0, 1, 0);
        rdB(c, 1, b1);
        WAIT_LGKM0(); SCHED0();
        mfma16(a0, b1, 0, 1);
        mfma16(a1, b1, 1, 1);
    }

    // ---- epilogue (R10 layout): row = wr*128+(mi>>2)*64+(mi&3)*16+(lane>>4)*4+j
    //                             col = wc*64 +(ni>>1)*32+(ni&1)*16+(lane&15)
    const int lc  = lane & 15;
    const int lr4 = (lane >> 4) * 4;
    float sarr[4], barr[4];
#pragma unroll
    for (int ni = 0; ni < 4; ++ni) {
        const int n = bcol * 256 + wc * 64 + (ni >> 1) * 32 + (ni & 1) * 16 + lc;
        sarr[ni] = scales[n];
        barr[ni] = bias[n];
    }
#pragma unroll
    for (int mi = 0; mi < 8; ++mi) {
        const int mb = brow * 256 + wr * 128 + (mi >> 2) * 64 + (mi & 3) * 16 + lr4;
#pragma unroll
        for (int j = 0; j < 4; ++j) {
            const size_t rowoff = (size_t)(mb + j) * N;
            const float sm = sx[mb + j];
#pragma unroll
            for (int ni = 0; ni < 4; ++ni) {
                const int n = bcol * 256 + wc * 64 + (ni >> 1) * 32 + (ni & 1) * 16 + lc;
                C[rowoff + n] = fmaf((float)acc[mi][ni][j], sm * sarr[ni], barr[ni]);
            }
        }
    }
}

// ---- Fallback: plain fp32 tiled GEMM, correctness insurance ----------------
__global__ void qlinear_fallback(const float* __restrict__ A,
                                 const float* __restrict__ B,
                                 const float* __restrict__ scales,
                                 const float* __restrict__ bias,
                                 float* __restrict__ C, int M, int N, int K) {
    __shared__ float As[16][17], Bs[16][17];
    const int tx = threadIdx.x, ty = threadIdx.y;
    const int row = blockIdx.y * 16 + ty;
    const int col = blockIdx.x * 16 + tx;
    float acc = 0.f;
    for (int k0 = 0; k0 < K; k0 += 16) {
        As[ty][tx] = A[(long)row * K + k0 + tx];
        Bs[ty][tx] = B[(long)(blockIdx.x * 16 + ty) * K + k0 + tx];
        __syncthreads();
#pragma unroll
        for (int kk = 0; kk < 16; ++kk) acc += As[ty][kk] * Bs[tx][kk];
        __syncthreads();
    }
    C[(long)row * N + col] = fmaf(acc, scales[col], bias[col]);
}

extern "C" void kernel_launch(void* const* d_in, const int* in_sizes, int n_in,
                              void* d_out, int out_size, void* d_ws, size_t ws_size,
                              hipStream_t stream) {
    const float* x      = (const float*)d_in[0];
    const float* w      = (const float*)d_in[1];
    const float* scales = (const float*)d_in[2];
    const float* bias   = (const float*)d_in[3];
    float* out = (float*)d_out;

    const int N = in_sizes[2];                  // 11008
    const int K = (int)((long)in_sizes[1] / N); // 4096
    const int M = (int)((long)in_sizes[0] / K); // 4096

    const size_t need = (size_t)M * K + (size_t)N * K + (size_t)M * 4;
    const bool ok = (ws_size >= need) && (M % 256) == 0 && (N % 256) == 0 &&
                    (K % 128) == 0 && (K / 128) >= 3 && (K % 16) == 0;

    if (ok) {
        char* xq = (char*)d_ws;
        char* wq = xq + (size_t)M * K;
        float* sxbuf = (float*)(wq + (size_t)N * K);

        x_quant_i8<<<M, 256, 0, stream>>>(x, (unsigned int*)xq, sxbuf, K);
        w_to_i8<<<2048, 256, 0, stream>>>(w, (u32x4*)wq, (long)N * K / 16);

        const int nbx = N / 256;
        const int nwg = (M / 256) * nbx;
        qlinear_gemm_i8k128<<<nwg, 512, 0, stream>>>(xq, wq, sxbuf, scales, bias,
                                                     out, M, N, K, nbx);
    } else {
        dim3 grid(N / 16, M / 16), blk(16, 16);
        qlinear_fallback<<<grid, blk, 0, stream>>>(x, w, scales, bias, out, M, N, K);
    }
}